// Round 3
// baseline (1561.193 us; speedup 1.0000x reference)
//
#include <hip/hip_runtime.h>
#include <hip/hip_fp16.h>
#include <cstdint>
#include <cstddef>

// Entropic Sinkhorn loss, MI355X / gfx950.  Round 3.
// G = K^T stored fp8 e5m2 (64 MiB), per-column(-of-G, = img index) power-of-2
// scaling. GEMM epilogue packs fp8 dwords via v_cvt_pk_bf8_f32 (C^T layout
// makes q-regs byte-consecutive). Sinkhorn matvec passes fused with the
// reciprocal transform via atomic column sums (triple-buffered, zeroed one
// pass ahead) -> 1 kernel per half-iteration.

#define N_DIM 8192
#define D_DIM 256
#define L2E100 144.26950408889634f  // 100 * log2(e)
#define BVAL (1.0f / 8192.0f)

typedef __attribute__((ext_vector_type(8))) short short8;
typedef __attribute__((ext_vector_type(4))) float f32x4;
typedef __attribute__((ext_vector_type(2))) float f32x2;

__device__ __forceinline__ float bf2f(unsigned short u) {
  union { unsigned int i; float f; } x; x.i = ((unsigned int)u) << 16; return x.f;
}
__device__ __forceinline__ unsigned short f2bf(float f) {
  union { float ff; unsigned int i; } x; x.ff = f;
  unsigned int r = x.i + 0x7FFFu + ((x.i >> 16) & 1u);
  return (unsigned short)(r >> 16);
}
// fp8 e5m2 (OCP) = top byte of f16.
__device__ __forceinline__ unsigned char f2bf8(float f) {
  union { __half h; unsigned short u; } x;
  x.h = __float2half(fminf(f, 57344.0f));
  unsigned short r = (unsigned short)(x.u + 0x7F + ((x.u >> 8) & 1));
  return (unsigned char)(r >> 8);
}
__device__ __forceinline__ float bf8tof(unsigned char b) {
  union { unsigned short u; __half h; } x; x.u = (unsigned short)((unsigned int)b << 8);
  return __half2float(x.h);
}
__device__ __forceinline__ void decode8(uint2 kv, float* k) {
#if __has_builtin(__builtin_amdgcn_cvt_pk_f32_bf8)
  f32x2 p;
  p = __builtin_amdgcn_cvt_pk_f32_bf8((int)kv.x, false); k[0] = p[0]; k[1] = p[1];
  p = __builtin_amdgcn_cvt_pk_f32_bf8((int)kv.x, true);  k[2] = p[0]; k[3] = p[1];
  p = __builtin_amdgcn_cvt_pk_f32_bf8((int)kv.y, false); k[4] = p[0]; k[5] = p[1];
  p = __builtin_amdgcn_cvt_pk_f32_bf8((int)kv.y, true);  k[6] = p[0]; k[7] = p[1];
#else
  #pragma unroll
  for (int i = 0; i < 4; ++i) k[i] = bf8tof((unsigned char)((kv.x >> (8 * i)) & 0xFF));
  #pragma unroll
  for (int i = 0; i < 4; ++i) k[4 + i] = bf8tof((unsigned char)((kv.y >> (8 * i)) & 0xFF));
#endif
}
__device__ __forceinline__ unsigned int pack4_bf8(float a, float b, float c, float d) {
#if __has_builtin(__builtin_amdgcn_cvt_pk_bf8_f32)
  int u = 0;
  u = __builtin_amdgcn_cvt_pk_bf8_f32(a, b, u, false);
  u = __builtin_amdgcn_cvt_pk_bf8_f32(c, d, u, true);
  return (unsigned int)u;
#else
  return (unsigned int)f2bf8(a) | ((unsigned int)f2bf8(b) << 8) |
         ((unsigned int)f2bf8(c) << 16) | ((unsigned int)f2bf8(d) << 24);
#endif
}
__device__ __forceinline__ float frcp(float x) { return __builtin_amdgcn_rcpf(x); }

#define GLD_LDS16(g, l)                                                          \
  __builtin_amdgcn_global_load_lds(                                              \
      (const __attribute__((address_space(1))) unsigned int*)(g),                \
      (__attribute__((address_space(3))) unsigned int*)(l), 16, 0, 0)

// ---------------- 1. fp32 -> bf16 cast ----------------
__global__ __launch_bounds__(256) void cast_bf16_kernel(const float* __restrict__ src,
                                                        unsigned short* __restrict__ dst,
                                                        int n4) {
  int i = blockIdx.x * blockDim.x + threadIdx.x;
  if (i < n4) {
    float4 f = reinterpret_cast<const float4*>(src)[i];
    ushort4 o;
    o.x = f2bf(f.x); o.y = f2bf(f.y); o.z = f2bf(f.z); o.w = f2bf(f.w);
    reinterpret_cast<ushort4*>(dst)[i] = o;
  }
}

// ---------------- 2. diagonal dot -> scale exponent E_i ----------------
__global__ __launch_bounds__(256) void diag_scale_kernel(const unsigned short* __restrict__ Abf,
                                                         const unsigned short* __restrict__ Bbf,
                                                         float* __restrict__ Ecol) {
  const int t = threadIdx.x, lane = t & 63, wid = t >> 6;
  const int rowg = lane >> 4, seg = lane & 15;
  const int row = blockIdx.x * 16 + wid * 4 + rowg;
  const unsigned short* a = Abf + (size_t)row * D_DIM + seg * 16;
  const unsigned short* b = Bbf + (size_t)row * D_DIM + seg * 16;
  float s = 0.0f;
  #pragma unroll
  for (int h = 0; h < 2; ++h) {
    short8 av = *reinterpret_cast<const short8*>(a + h * 8);
    short8 bv = *reinterpret_cast<const short8*>(b + h * 8);
    #pragma unroll
    for (int e = 0; e < 8; ++e)
      s += bf2f((unsigned short)av[e]) * bf2f((unsigned short)bv[e]);
  }
  s += __shfl_xor(s, 1, 64); s += __shfl_xor(s, 2, 64);
  s += __shfl_xor(s, 4, 64); s += __shfl_xor(s, 8, 64);
  if (seg == 0) Ecol[row] = rintf((1.0f - s) * L2E100);
}

// ---------------- 3. GEMM + exp2 + scale -> fp8 G = K^T ----------------
// 128x128 tile, BK=32, 4 waves (2x2), wave tile 64x64. Double-buffered
// global_load_lds staging, XOR pre-swizzle (source+read). Epilogue: C^T pack
// (q-regs = consecutive bytes) via cvt_pk_bf8 -> dword LDS repack -> uint4 stores.
__global__ __launch_bounds__(256) void gemm_exp_fp8_kernel(const unsigned short* __restrict__ A,
                                                           const unsigned short* __restrict__ B,
                                                           const float* __restrict__ Ecol,
                                                           unsigned char* __restrict__ Kout) {
  __shared__ __align__(16) char smem[32768];
  const int bi = blockIdx.y, bj = blockIdx.x;
  const int t = threadIdx.x, lane = t & 63, wid = t >> 6;
  const int wr = wid >> 1, wc = wid & 1;
  const int al = lane & 15, kh = lane >> 4;

  const int sr = t >> 2, scb = t & 3;
  const int r0 = sr, r1 = sr + 64;
  const int g0 = scb ^ ((r0 + (r0 >> 2)) & 3);
  const int g1 = scb ^ ((r1 + (r1 >> 2)) & 3);
  const unsigned short* A0 = A + (size_t)(bi * 128 + r0) * D_DIM + g0 * 8;
  const unsigned short* A1 = A + (size_t)(bi * 128 + r1) * D_DIM + g1 * 8;
  const unsigned short* B0 = B + (size_t)(bj * 128 + r0) * D_DIM + g0 * 8;
  const unsigned short* B1 = B + (size_t)(bj * 128 + r1) * D_DIM + g1 * 8;

  // eadj[m][q] = E_i - L2E100 for i = bi*128 + wr*64 + m*16 + kh*4 + q
  float eadj[4][4];
  #pragma unroll
  for (int m = 0; m < 4; ++m) {
    float4 e = *reinterpret_cast<const float4*>(Ecol + bi * 128 + wr * 64 + m * 16 + kh * 4);
    eadj[m][0] = e.x - L2E100; eadj[m][1] = e.y - L2E100;
    eadj[m][2] = e.z - L2E100; eadj[m][3] = e.w - L2E100;
  }

  int offA[4], offB[4];
  #pragma unroll
  for (int m = 0; m < 4; ++m) {
    int ra = wr * 64 + m * 16 + al;
    offA[m] = ra * 64 + ((kh ^ ((ra + (ra >> 2)) & 3)) << 4);
    int rb = wc * 64 + m * 16 + al;
    offB[m] = rb * 64 + ((kh ^ ((rb + (rb >> 2)) & 3)) << 4);
  }

  f32x4 acc[4][4] = {};

  #define STAGE(kk, buf)                                        \
    do {                                                        \
      char* sb = smem + (buf) * 16384;                          \
      GLD_LDS16(A0 + (kk) * 32, sb + t * 16);                   \
      GLD_LDS16(A1 + (kk) * 32, sb + 4096 + t * 16);            \
      GLD_LDS16(B0 + (kk) * 32, sb + 8192 + t * 16);            \
      GLD_LDS16(B1 + (kk) * 32, sb + 12288 + t * 16);           \
    } while (0)

  STAGE(0, 0);
  __syncthreads();
  #pragma unroll
  for (int kk = 0; kk < 8; ++kk) {
    const int buf = kk & 1;
    if (kk < 7) STAGE(kk + 1, buf ^ 1);
    const char* sb = smem + buf * 16384;
    short8 a[4], b[4];
    #pragma unroll
    for (int m = 0; m < 4; ++m) a[m] = *reinterpret_cast<const short8*>(sb + offA[m]);
    #pragma unroll
    for (int n = 0; n < 4; ++n) b[n] = *reinterpret_cast<const short8*>(sb + 8192 + offB[n]);
    #pragma unroll
    for (int m = 0; m < 4; ++m)
      #pragma unroll
      for (int n = 0; n < 4; ++n)
        acc[m][n] = __builtin_amdgcn_mfma_f32_16x16x32_bf16(a[m], b[n], acc[m][n], 0, 0, 0);
    __syncthreads();
  }
  #undef STAGE

  // epilogue: G[jloc][iloc] tile (128x128 bytes), LDS rows stride 144B.
  // value(m,n,q): jloc = wc*64+n*16+al, iloc = wr*64+m*16+kh*4+q.
  unsigned int* Cs32 = (unsigned int*)smem;  // [jloc][36 dwords]
  #pragma unroll
  for (int m = 0; m < 4; ++m) {
    const int ib4 = wr * 16 + m * 4 + kh;  // dword index in row
    #pragma unroll
    for (int n = 0; n < 4; ++n) {
      float g[4];
      #pragma unroll
      for (int q = 0; q < 4; ++q)
        g[q] = exp2f(fminf(fmaf(acc[m][n][q], L2E100, eadj[m][q]), 14.0f));
      const int jloc = wc * 64 + n * 16 + al;
      Cs32[jloc * 36 + ib4] = pack4_bf8(g[0], g[1], g[2], g[3]);
    }
  }
  __syncthreads();
  const int jl = t >> 1, hf = (t & 1) * 64;
  const unsigned char* Crow = (const unsigned char*)smem + jl * 144 + hf;
  size_t gb = (size_t)(bj * 128 + jl) * N_DIM + bi * 128 + hf;
  #pragma unroll
  for (int c = 0; c < 4; ++c)
    *reinterpret_cast<uint4*>(Kout + gb + c * 16) =
        *reinterpret_cast<const uint4*>(Crow + c * 16);
}

// ---------------- 4. init: ones buffer, first atomic col buffer, out ----------------
__global__ __launch_bounds__(256) void init_kernel(float* __restrict__ ones,
                                                   float* __restrict__ cb0,
                                                   float* __restrict__ out) {
  int i = blockIdx.x * blockDim.x + threadIdx.x;
  if (i < N_DIM) { ones[i] = 1.0f; cb0[i] = 0.0f; }
  if (i == 0) out[0] = 0.0f;
}

// ---------------- 5. fused dual matvec ----------------
// weights: wrow_i = coeff/rowPrev_i, wcol_j = coeff/colPrev_j (computed inline).
// rowOut_i = sum_j G_ij*wcol_j (direct; block owns full rows);
// colOut_j += sum_{i in stripe} G_ij*wrow_i (device atomics, buffer pre-zeroed);
// also zeroes colZero's 32-col slice for the pass after next.
__global__ __launch_bounds__(1024) void dual_matvec_fused_kernel(
    const unsigned char* __restrict__ K8,
    const float* __restrict__ rowPrev, const float* __restrict__ colPrev,
    float* __restrict__ rowOut, float* __restrict__ colOut,
    float* __restrict__ colZero, float coeff) {
  const int b = blockIdx.x, t = threadIdx.x;
  const int c0 = t * 8, row0 = b * 32;
  if (t < 8)
    *reinterpret_cast<float4*>(colZero + b * 32 + t * 4) = make_float4(0.f, 0.f, 0.f, 0.f);
  float wc8[8];
  {
    float4 p0 = *reinterpret_cast<const float4*>(colPrev + c0);
    float4 p1 = *reinterpret_cast<const float4*>(colPrev + c0 + 4);
    wc8[0] = coeff * frcp(p0.x); wc8[1] = coeff * frcp(p0.y);
    wc8[2] = coeff * frcp(p0.z); wc8[3] = coeff * frcp(p0.w);
    wc8[4] = coeff * frcp(p1.x); wc8[5] = coeff * frcp(p1.y);
    wc8[6] = coeff * frcp(p1.z); wc8[7] = coeff * frcp(p1.w);
  }
  float colacc[8] = {0, 0, 0, 0, 0, 0, 0, 0};
  __shared__ float pbuf[8][1024];

  for (int batch = 0; batch < 4; ++batch) {
    #pragma unroll
    for (int rr = 0; rr < 8; ++rr) {
      const int r = batch * 8 + rr;
      const float wr = coeff * frcp(rowPrev[row0 + r]);
      uint2 kv = *reinterpret_cast<const uint2*>(K8 + (size_t)(row0 + r) * N_DIM + c0);
      float k[8];
      decode8(kv, k);
      float p = 0.0f;
      #pragma unroll
      for (int e = 0; e < 8; ++e) {
        p += k[e] * wc8[e];
        colacc[e] += k[e] * wr;
      }
      pbuf[rr][t] = p;
    }
    __syncthreads();
    if (t < 512) {
      const int w = t >> 6, l = t & 63;
      float s = 0.0f;
      #pragma unroll
      for (int i = 0; i < 16; ++i) s += pbuf[w][l + i * 64];
      #pragma unroll
      for (int off = 32; off > 0; off >>= 1) s += __shfl_down(s, off, 64);
      if (l == 0) rowOut[row0 + batch * 8 + w] = s;
    }
    __syncthreads();
  }
  #pragma unroll
  for (int e = 0; e < 8; ++e) atomicAdd(colOut + c0 + e, colacc[e]);
}

// ---------------- 6. final pass: softmax denominators ----------------
// u1_i = 1/rb1_i, v1_j = b/cb2_j, u2_j = 1/cb0_j, v2_i = b/rb0_i  (inline).
// rowE_i = sum_j exp(u1_i G_ij v1_j); colE_j += sum_i exp(u2_j G_ij v2_i).
__global__ __launch_bounds__(1024) void final_dual_fused_kernel(
    const unsigned char* __restrict__ K8,
    const float* __restrict__ rb1, const float* __restrict__ cb2,
    const float* __restrict__ cb0, const float* __restrict__ rb0,
    float* __restrict__ rowE, float* __restrict__ colE) {
  const int b = blockIdx.x, t = threadIdx.x;
  const int c0 = t * 8, row0 = b * 32;
  float v1_8[8], u2_8[8];
  {
    float4 p0 = *reinterpret_cast<const float4*>(cb2 + c0);
    float4 p1 = *reinterpret_cast<const float4*>(cb2 + c0 + 4);
    v1_8[0] = BVAL * frcp(p0.x); v1_8[1] = BVAL * frcp(p0.y);
    v1_8[2] = BVAL * frcp(p0.z); v1_8[3] = BVAL * frcp(p0.w);
    v1_8[4] = BVAL * frcp(p1.x); v1_8[5] = BVAL * frcp(p1.y);
    v1_8[6] = BVAL * frcp(p1.z); v1_8[7] = BVAL * frcp(p1.w);
    float4 q0 = *reinterpret_cast<const float4*>(cb0 + c0);
    float4 q1 = *reinterpret_cast<const float4*>(cb0 + c0 + 4);
    u2_8[0] = frcp(q0.x); u2_8[1] = frcp(q0.y); u2_8[2] = frcp(q0.z); u2_8[3] = frcp(q0.w);
    u2_8[4] = frcp(q1.x); u2_8[5] = frcp(q1.y); u2_8[6] = frcp(q1.z); u2_8[7] = frcp(q1.w);
  }
  float colacc[8] = {0, 0, 0, 0, 0, 0, 0, 0};
  __shared__ float pbuf[8][1024];

  for (int batch = 0; batch < 4; ++batch) {
    #pragma unroll
    for (int rr = 0; rr < 8; ++rr) {
      const int r = batch * 8 + rr;
      const float u1 = frcp(rb1[row0 + r]);
      const float v2i = BVAL * frcp(rb0[row0 + r]);
      uint2 kv = *reinterpret_cast<const uint2*>(K8 + (size_t)(row0 + r) * N_DIM + c0);
      float k[8];
      decode8(kv, k);
      float p = 0.0f;
      #pragma unroll
      for (int e = 0; e < 8; ++e) {
        p += __expf(u1 * k[e] * v1_8[e]);
        colacc[e] += __expf(u2_8[e] * k[e] * v2i);
      }
      pbuf[rr][t] = p;
    }
    __syncthreads();
    if (t < 512) {
      const int w = t >> 6, l = t & 63;
      float s = 0.0f;
      #pragma unroll
      for (int i = 0; i < 16; ++i) s += pbuf[w][l + i * 64];
      #pragma unroll
      for (int off = 32; off > 0; off >>= 1) s += __shfl_down(s, off, 64);
      if (l == 0) rowE[row0 + batch * 8 + w] = s;
    }
    __syncthreads();
  }
  #pragma unroll
  for (int e = 0; e < 8; ++e) atomicAdd(colE + c0 + e, colacc[e]);
}

// ---------------- 7. final scalar loss ----------------
__global__ __launch_bounds__(256) void final_loss_kernel(
    const unsigned char* __restrict__ K8,
    const float* __restrict__ rowE, const float* __restrict__ colE,
    const float* __restrict__ rb1, const float* __restrict__ cb2,
    const float* __restrict__ cb0, const float* __restrict__ rb0,
    float* __restrict__ out) {
  const int i = blockIdx.x * 256 + threadIdx.x;
  const float kd = bf8tof(K8[(size_t)i * (N_DIM + 1)]);
  const float u1 = frcp(rb1[i]), v1 = BVAL * frcp(cb2[i]);
  const float u2 = frcp(cb0[i]), v2 = BVAL * frcp(rb0[i]);
  float val = (logf(rowE[i]) - u1 * kd * v1) + (logf(colE[i]) - u2 * kd * v2);
  #pragma unroll
  for (int o = 32; o > 0; o >>= 1) val += __shfl_down(val, o, 64);
  __shared__ float red[4];
  if ((threadIdx.x & 63) == 0) red[threadIdx.x >> 6] = val;
  __syncthreads();
  if (threadIdx.x == 0) {
    float s = red[0] + red[1] + red[2] + red[3];
    atomicAdd(out, s * (0.5f / (float)N_DIM));
  }
}

// ---------------- launch ----------------
extern "C" void kernel_launch(void* const* d_in, const int* in_sizes, int n_in,
                              void* d_out, int out_size, void* d_ws, size_t ws_size,
                              hipStream_t stream) {
  const float* img = (const float*)d_in[0];
  const float* txt = (const float*)d_in[1];
  float* out = (float*)d_out;

  char* ws = (char*)d_ws;
  size_t off = 0;
  auto alloc = [&](size_t bytes) -> void* {
    void* p = ws + off;
    off += (bytes + 255) & ~(size_t)255;
    return p;
  };
  unsigned char* K8   = (unsigned char*)alloc((size_t)N_DIM * N_DIM);  // 64 MiB
  unsigned short* Abf = (unsigned short*)alloc((size_t)N_DIM * D_DIM * 2);
  unsigned short* Bbf = (unsigned short*)alloc((size_t)N_DIM * D_DIM * 2);
  float* Ecol = (float*)alloc(N_DIM * 4);
  float* ones = (float*)alloc(N_DIM * 4);
  float* rb0  = (float*)alloc(N_DIM * 4);
  float* rb1  = (float*)alloc(N_DIM * 4);
  float* cb0  = (float*)alloc(N_DIM * 4);
  float* cb1  = (float*)alloc(N_DIM * 4);
  float* cb2  = (float*)alloc(N_DIM * 4);
  float* rowE = (float*)alloc(N_DIM * 4);

  if (off > ws_size) {
    hipMemsetAsync(d_out, 0xFF, sizeof(float) * (out_size > 0 ? out_size : 1), stream);
    return;
  }

  float* rb[2] = {rb0, rb1};
  float* cb[3] = {cb0, cb1, cb2};

  const int n4 = N_DIM * D_DIM / 4;
  cast_bf16_kernel<<<(n4 + 255) / 256, 256, 0, stream>>>(img, Abf, n4);
  cast_bf16_kernel<<<(n4 + 255) / 256, 256, 0, stream>>>(txt, Bbf, n4);
  diag_scale_kernel<<<512, 256, 0, stream>>>(Abf, Bbf, Ecol);
  gemm_exp_fp8_kernel<<<dim3(64, 64), 256, 0, stream>>>(Abf, Bbf, Ecol, K8);
  init_kernel<<<32, 256, 0, stream>>>(ones, cb0, out);

  for (int p = 0; p < 10; ++p) {
    const float* rowPrev = (p == 0) ? ones : rb[(p - 1) & 1];
    const float* colPrev = (p == 0) ? ones : cb[(p - 1) % 3];
    const float coeff = (p == 0 || (p & 1)) ? BVAL : 1.0f;
    dual_matvec_fused_kernel<<<256, 1024, 0, stream>>>(
        K8, rowPrev, colPrev, rb[p & 1], cb[p % 3], cb[(p + 1) % 3], coeff);
  }
  // after pass 9: rowB5=rb[1], colB5=cb[0], rowA5=rb[0], colA5=cb[2]; cb[1] zeroed.
  final_dual_fused_kernel<<<256, 1024, 0, stream>>>(K8, rb1, cb2, cb0, rb0, rowE, cb1);
  final_loss_kernel<<<32, 256, 0, stream>>>(K8, rowE, cb1, rb1, cb2, cb0, rb0, out);
}

// Round 4
// 307.713 us; speedup vs baseline: 5.0735x; 5.0735x over previous
//
#include <hip/hip_runtime.h>
#include <hip/hip_fp16.h>
#include <cstdint>
#include <cstddef>

// Entropic Sinkhorn loss, MI355X / gfx950.  Round 4.
// Key insight: after per-column power-of-2 scaling (diag exponent ~0), ALL
// off-diagonal entries of K quantize to 0 in fp8 e5m2 (exponents -40..-110).
// R2/R3 validated the quantized math dense (absmax 0.0). So K is never
// materialized: the GEMM epilogue emits a sparse COO list (exact fp8-byte
// semantics) + dense Gdiag; the whole Sinkhorn iteration (10 passes + final
// log-softmax pass + loss) runs in ONE single-block kernel on ~8-20K entries
// with LDS accumulators (no device-scope atomics -- R3's 2M far-atomics/pass
// was the regression).

#define N_DIM 8192
#define D_DIM 256
#define L2E100 144.26950408889634f  // 100 * log2(e)
#define BVAL (1.0f / 8192.0f)
#define NNZ_CAP (1u << 22)          // 4M entries (32 MiB), ~500x expected nnz

typedef __attribute__((ext_vector_type(8))) short short8;
typedef __attribute__((ext_vector_type(4))) float f32x4;

__device__ __forceinline__ float bf2f(unsigned short u) {
  union { unsigned int i; float f; } x; x.i = ((unsigned int)u) << 16; return x.f;
}
__device__ __forceinline__ unsigned short f2bf(float f) {
  union { float ff; unsigned int i; } x; x.ff = f;
  unsigned int r = x.i + 0x7FFFu + ((x.i >> 16) & 1u);
  return (unsigned short)(r >> 16);
}
// fp8 e5m2 (OCP) = top byte of f16.
__device__ __forceinline__ unsigned char f2bf8(float f) {
  union { __half h; unsigned short u; } x;
  x.h = __float2half(fminf(f, 57344.0f));
  unsigned short r = (unsigned short)(x.u + 0x7F + ((x.u >> 8) & 1));
  return (unsigned char)(r >> 8);
}
__device__ __forceinline__ float bf8tof(unsigned char b) {
  union { unsigned short u; __half h; } x; x.u = (unsigned short)((unsigned int)b << 8);
  return __half2float(x.h);
}
__device__ __forceinline__ unsigned int pack4_bf8(float a, float b, float c, float d) {
#if __has_builtin(__builtin_amdgcn_cvt_pk_bf8_f32)
  int u = 0;
  u = __builtin_amdgcn_cvt_pk_bf8_f32(a, b, u, false);   // bytes 0,1
  u = __builtin_amdgcn_cvt_pk_bf8_f32(c, d, u, true);    // bytes 2,3
  return (unsigned int)u;
#else
  return (unsigned int)f2bf8(a) | ((unsigned int)f2bf8(b) << 8) |
         ((unsigned int)f2bf8(c) << 16) | ((unsigned int)f2bf8(d) << 24);
#endif
}
__device__ __forceinline__ float frcp(float x) { return __builtin_amdgcn_rcpf(x); }

#define GLD_LDS16(g, l)                                                          \
  __builtin_amdgcn_global_load_lds(                                              \
      (const __attribute__((address_space(1))) unsigned int*)(g),                \
      (__attribute__((address_space(3))) unsigned int*)(l), 16, 0, 0)

// ---------------- 1. fp32 -> bf16 cast ----------------
__global__ __launch_bounds__(256) void cast_bf16_kernel(const float* __restrict__ src,
                                                        unsigned short* __restrict__ dst,
                                                        int n4) {
  int i = blockIdx.x * blockDim.x + threadIdx.x;
  if (i < n4) {
    float4 f = reinterpret_cast<const float4*>(src)[i];
    ushort4 o;
    o.x = f2bf(f.x); o.y = f2bf(f.y); o.z = f2bf(f.z); o.w = f2bf(f.w);
    reinterpret_cast<ushort4*>(dst)[i] = o;
  }
}

// ---------------- 2. diagonal dot -> scale exponent E_i ----------------
__global__ __launch_bounds__(256) void diag_scale_kernel(const unsigned short* __restrict__ Abf,
                                                         const unsigned short* __restrict__ Bbf,
                                                         float* __restrict__ Ecol) {
  const int t = threadIdx.x, lane = t & 63, wid = t >> 6;
  const int rowg = lane >> 4, seg = lane & 15;
  const int row = blockIdx.x * 16 + wid * 4 + rowg;
  const unsigned short* a = Abf + (size_t)row * D_DIM + seg * 16;
  const unsigned short* b = Bbf + (size_t)row * D_DIM + seg * 16;
  float s = 0.0f;
  #pragma unroll
  for (int h = 0; h < 2; ++h) {
    short8 av = *reinterpret_cast<const short8*>(a + h * 8);
    short8 bv = *reinterpret_cast<const short8*>(b + h * 8);
    #pragma unroll
    for (int e = 0; e < 8; ++e)
      s += bf2f((unsigned short)av[e]) * bf2f((unsigned short)bv[e]);
  }
  s += __shfl_xor(s, 1, 64); s += __shfl_xor(s, 2, 64);
  s += __shfl_xor(s, 4, 64); s += __shfl_xor(s, 8, 64);
  if (seg == 0) Ecol[row] = rintf((1.0f - s) * L2E100);
}

// ---------------- 3. init: nnz counter + out ----------------
__global__ void init_kernel(unsigned int* __restrict__ cnt, float* __restrict__ out) {
  if (threadIdx.x == 0) { cnt[0] = 0u; out[0] = 0.0f; }
}

// ---------------- 4. GEMM + exp2 + scale -> sparse fp8-quantized entries ----------------
// 128x128 tile, BK=32, 4 waves (2x2), wave tile 64x64. Double-buffered
// global_load_lds staging, XOR pre-swizzle (source+read). Epilogue: compute
// g = exp2((S-1)*L2E100 + E_i); pack to fp8 bytes; byte!=0 => append
// (r=txt j, c=img i, decoded value) to COO list. Diagonal -> Gdiag dense.
__global__ __launch_bounds__(256) void gemm_sparse_kernel(const unsigned short* __restrict__ A,
                                                          const unsigned short* __restrict__ B,
                                                          const float* __restrict__ Ecol,
                                                          uint2* __restrict__ entries,
                                                          unsigned int* __restrict__ cnt,
                                                          float* __restrict__ Gdiag) {
  __shared__ __align__(16) char smem[32768];
  const int bi = blockIdx.y, bj = blockIdx.x;
  const int t = threadIdx.x, lane = t & 63, wid = t >> 6;
  const int wr = wid >> 1, wc = wid & 1;
  const int al = lane & 15, kh = lane >> 4;

  const int sr = t >> 2, scb = t & 3;
  const int r0 = sr, r1 = sr + 64;
  const int g0 = scb ^ ((r0 + (r0 >> 2)) & 3);
  const int g1 = scb ^ ((r1 + (r1 >> 2)) & 3);
  const unsigned short* A0 = A + (size_t)(bi * 128 + r0) * D_DIM + g0 * 8;
  const unsigned short* A1 = A + (size_t)(bi * 128 + r1) * D_DIM + g1 * 8;
  const unsigned short* B0 = B + (size_t)(bj * 128 + r0) * D_DIM + g0 * 8;
  const unsigned short* B1 = B + (size_t)(bj * 128 + r1) * D_DIM + g1 * 8;

  // eadj[m][q] = E_i - L2E100 for i = bi*128 + wr*64 + m*16 + kh*4 + q
  float eadj[4][4];
  #pragma unroll
  for (int m = 0; m < 4; ++m) {
    float4 e = *reinterpret_cast<const float4*>(Ecol + bi * 128 + wr * 64 + m * 16 + kh * 4);
    eadj[m][0] = e.x - L2E100; eadj[m][1] = e.y - L2E100;
    eadj[m][2] = e.z - L2E100; eadj[m][3] = e.w - L2E100;
  }

  int offA[4], offB[4];
  #pragma unroll
  for (int m = 0; m < 4; ++m) {
    int ra = wr * 64 + m * 16 + al;
    offA[m] = ra * 64 + ((kh ^ ((ra + (ra >> 2)) & 3)) << 4);
    int rb = wc * 64 + m * 16 + al;
    offB[m] = rb * 64 + ((kh ^ ((rb + (rb >> 2)) & 3)) << 4);
  }

  f32x4 acc[4][4] = {};

  #define STAGE(kk, buf)                                        \
    do {                                                        \
      char* sb = smem + (buf) * 16384;                          \
      GLD_LDS16(A0 + (kk) * 32, sb + t * 16);                   \
      GLD_LDS16(A1 + (kk) * 32, sb + 4096 + t * 16);            \
      GLD_LDS16(B0 + (kk) * 32, sb + 8192 + t * 16);            \
      GLD_LDS16(B1 + (kk) * 32, sb + 12288 + t * 16);           \
    } while (0)

  STAGE(0, 0);
  __syncthreads();
  #pragma unroll
  for (int kk = 0; kk < 8; ++kk) {
    const int buf = kk & 1;
    if (kk < 7) STAGE(kk + 1, buf ^ 1);
    const char* sb = smem + buf * 16384;
    short8 a[4], b[4];
    #pragma unroll
    for (int m = 0; m < 4; ++m) a[m] = *reinterpret_cast<const short8*>(sb + offA[m]);
    #pragma unroll
    for (int n = 0; n < 4; ++n) b[n] = *reinterpret_cast<const short8*>(sb + 8192 + offB[n]);
    #pragma unroll
    for (int m = 0; m < 4; ++m)
      #pragma unroll
      for (int n = 0; n < 4; ++n)
        acc[m][n] = __builtin_amdgcn_mfma_f32_16x16x32_bf16(a[m], b[n], acc[m][n], 0, 0, 0);
    __syncthreads();
  }
  #undef STAGE

  // epilogue: value(m,n,q) at img index i = bi*128+wr*64+m*16+kh*4+q,
  //                        txt index j = bj*128+wc*64+n*16+al.
  // G rows = j (txt), cols = i (img), per-col(i) scaled (matches R3 dense).
  #pragma unroll
  for (int m = 0; m < 4; ++m) {
    #pragma unroll
    for (int n = 0; n < 4; ++n) {
      float x[4];
      #pragma unroll
      for (int q = 0; q < 4; ++q) x[q] = fmaf(acc[m][n][q], L2E100, eadj[m][q]);
      float mx = fmaxf(fmaxf(x[0], x[1]), fmaxf(x[2], x[3]));
      if (mx > -19.5f) {  // anything below can't round to a nonzero e5m2 byte
        unsigned int w = pack4_bf8(exp2f(fminf(x[0], 14.0f)), exp2f(fminf(x[1], 14.0f)),
                                   exp2f(fminf(x[2], 14.0f)), exp2f(fminf(x[3], 14.0f)));
        if (w != 0u) {
          const int jg = bj * 128 + wc * 64 + n * 16 + al;
          const int ib = bi * 128 + wr * 64 + m * 16 + kh * 4;
          #pragma unroll
          for (int q = 0; q < 4; ++q) {
            unsigned int byte = (w >> (8 * q)) & 0xFFu;
            if (byte) {
              float gv = bf8tof((unsigned char)byte);
              const int ig = ib + q;
              unsigned int slot = atomicAdd(cnt, 1u);
              if (slot < NNZ_CAP)
                entries[slot] = make_uint2(((unsigned int)jg << 13) | (unsigned int)ig,
                                           __float_as_uint(gv));
              if (ig == jg) Gdiag[ig] = gv;
            }
          }
        }
      }
    }
  }
}

// ---------------- 5. full Sinkhorn + loss, single block ----------------
// 10 passes + final pass + scalar loss over the sparse entry list.
// Pass p (mirrors the verified dense schedule):
//   wrow_r = coeff*rcp(rowPrev[r]), wcol_c = coeff*rcp(colPrev[c]) (p=0: BVAL)
//   rowOut[r] = sum_c G_rc*wcol_c ; colOut[c] = sum_r G_rc*wrow_r
// outputs cycle rb[p&1], cb[p%3]; coeff = BVAL for p==0 or p odd, else 1.
// Final: u1=rcp(rb1[r]), v1=BVAL*rcp(cb2[c]), u2=rcp(cb0[c]), v2=BVAL*rcp(rb0[r]);
//   rowE[r] = 8192 + sum expm1(u1*g*v1); colE[c] = 8192 + sum expm1(u2*g*v2);
//   loss = 0.5/n * sum_i [log rowE_i - u1*gd*v1 + log colE_i - u2*gd*v2].
__global__ __launch_bounds__(1024) void sinkhorn_sparse_kernel(
    const uint2* __restrict__ entries, const unsigned int* __restrict__ pCnt,
    const float* __restrict__ Gdiag,
    float* __restrict__ rb0, float* __restrict__ rb1,
    float* __restrict__ cb0, float* __restrict__ cb1, float* __restrict__ cb2,
    float* __restrict__ out) {
  const int t = threadIdx.x;
  __shared__ float rowAcc[8192];
  __shared__ float colAcc[8192];
  const unsigned int raw = pCnt[0];
  const int nnz = (int)(raw > NNZ_CAP ? NNZ_CAP : raw);

  #pragma unroll
  for (int p = 0; p < 10; ++p) {
    for (int i = t; i < 8192; i += 1024) { rowAcc[i] = 0.0f; colAcc[i] = 0.0f; }
    __syncthreads();
    const float coeff = (p == 0 || (p & 1)) ? BVAL : 1.0f;
    const float* rowPrev = (p == 0) ? rb0 : ((p - 1) & 1 ? rb1 : rb0);
    const float* colPrev = (p == 0) ? cb0 : ((p - 1) % 3 == 0 ? cb0 : ((p - 1) % 3 == 1 ? cb1 : cb2));
    for (int e = t; e < nnz; e += 1024) {
      const uint2 en = entries[e];
      const int c = (int)(en.x & 8191u);   // img index
      const int r = (int)(en.x >> 13);     // txt index
      const float g = __uint_as_float(en.y);
      const float wr = (p == 0) ? BVAL : coeff * frcp(rowPrev[r]);
      const float wc = (p == 0) ? BVAL : coeff * frcp(colPrev[c]);
      atomicAdd(&rowAcc[r], g * wc);
      atomicAdd(&colAcc[c], g * wr);
    }
    __syncthreads();
    float* rowOut = (p & 1) ? rb1 : rb0;
    float* colOut = (p % 3 == 0) ? cb0 : ((p % 3 == 1) ? cb1 : cb2);
    for (int i = t; i < 8192; i += 1024) { rowOut[i] = rowAcc[i]; colOut[i] = colAcc[i]; }
    __syncthreads();
  }

  // final pass
  for (int i = t; i < 8192; i += 1024) { rowAcc[i] = 0.0f; colAcc[i] = 0.0f; }
  __syncthreads();
  for (int e = t; e < nnz; e += 1024) {
    const uint2 en = entries[e];
    const int c = (int)(en.x & 8191u);
    const int r = (int)(en.x >> 13);
    const float g = __uint_as_float(en.y);
    const float u1 = frcp(rb1[r]);
    const float v1 = BVAL * frcp(cb2[c]);
    const float u2 = frcp(cb0[c]);
    const float v2 = BVAL * frcp(rb0[r]);
    atomicAdd(&rowAcc[r], __expf(u1 * g * v1) - 1.0f);
    atomicAdd(&colAcc[c], __expf(u2 * g * v2) - 1.0f);
  }
  __syncthreads();

  // loss
  float val = 0.0f;
  for (int i = t; i < 8192; i += 1024) {
    const float gd = Gdiag[i];
    const float u1 = frcp(rb1[i]), v1 = BVAL * frcp(cb2[i]);
    const float u2 = frcp(cb0[i]), v2 = BVAL * frcp(rb0[i]);
    val += (logf(8192.0f + rowAcc[i]) - u1 * gd * v1)
         + (logf(8192.0f + colAcc[i]) - u2 * gd * v2);
  }
  #pragma unroll
  for (int o = 32; o > 0; o >>= 1) val += __shfl_down(val, o, 64);
  __syncthreads();                       // all reads of rowAcc done
  if ((t & 63) == 0) rowAcc[t >> 6] = val;
  __syncthreads();
  if (t == 0) {
    float s = 0.0f;
    #pragma unroll
    for (int w = 0; w < 16; ++w) s += rowAcc[w];
    s *= 0.5f / 8192.0f;
    if (raw > NNZ_CAP) s = __int_as_float(0x7FC00000);  // fail loudly, never silently
    out[0] = s;
  }
}

// ---------------- launch ----------------
extern "C" void kernel_launch(void* const* d_in, const int* in_sizes, int n_in,
                              void* d_out, int out_size, void* d_ws, size_t ws_size,
                              hipStream_t stream) {
  const float* img = (const float*)d_in[0];
  const float* txt = (const float*)d_in[1];
  float* out = (float*)d_out;

  char* ws = (char*)d_ws;
  size_t off = 0;
  auto alloc = [&](size_t bytes) -> void* {
    void* p = ws + off;
    off += (bytes + 255) & ~(size_t)255;
    return p;
  };
  unsigned short* Abf = (unsigned short*)alloc((size_t)N_DIM * D_DIM * 2);  // 4 MiB
  unsigned short* Bbf = (unsigned short*)alloc((size_t)N_DIM * D_DIM * 2);  // 4 MiB
  uint2* entries      = (uint2*)alloc((size_t)NNZ_CAP * 8);                 // 32 MiB
  unsigned int* cnt   = (unsigned int*)alloc(256);
  float* Ecol  = (float*)alloc(N_DIM * 4);
  float* Gdiag = (float*)alloc(N_DIM * 4);
  float* rb0   = (float*)alloc(N_DIM * 4);
  float* rb1   = (float*)alloc(N_DIM * 4);
  float* cb0   = (float*)alloc(N_DIM * 4);
  float* cb1   = (float*)alloc(N_DIM * 4);
  float* cb2   = (float*)alloc(N_DIM * 4);

  if (off > ws_size) {
    hipMemsetAsync(d_out, 0xFF, sizeof(float) * (out_size > 0 ? out_size : 1), stream);
    return;
  }

  const int n4 = N_DIM * D_DIM / 4;
  cast_bf16_kernel<<<(n4 + 255) / 256, 256, 0, stream>>>(img, Abf, n4);
  cast_bf16_kernel<<<(n4 + 255) / 256, 256, 0, stream>>>(txt, Bbf, n4);
  diag_scale_kernel<<<512, 256, 0, stream>>>(Abf, Bbf, Ecol);
  init_kernel<<<1, 64, 0, stream>>>(cnt, out);
  gemm_sparse_kernel<<<dim3(64, 64), 256, 0, stream>>>(Abf, Bbf, Ecol, entries, cnt, Gdiag);
  sinkhorn_sparse_kernel<<<1, 1024, 0, stream>>>(entries, cnt, Gdiag,
                                                 rb0, rb1, cb0, cb1, cb2, out);
}